// Round 12
// baseline (109.681 us; speedup 1.0000x reference)
//
#include <hip/hip_runtime.h>

#define GS3 2097152          // 128^3
#define NS1 262144           // 64^3
#define NS2 32768            // 32^3
#define NS3 4096             // 16^3
#define NS4 512              // 8^3
#define NS5 64               // 4^3
#define NSALL 299584         // NS1+NS2+NS3+NS4+NS5

// Output element offsets (float index) for each scale's block of [Ss^3, 12]
#define OB1 25165824
#define OB2 28311552
#define OB3 28704768
#define OB4 28753920
#define OB5 28760064

#define NREG 512             // regions: x-pair (x>>1, 6b) * y-16th (y>>4, 3b)
#define RVOX 4096            // voxels per region: 2(x) * 16(y) * 128(z) = 16KB LDS
#define CAP  10240           // bin capacity per region (mean 7813, +27 sigma)
#define PPB  4096            // points per binning block (39.3KB LDS -> 4 blk/CU)

// Record: (region<<18) | (localvoxel<<6) | label
//   region   = (x>>1)<<3 | (y>>4)             (9 bits)
//   localvox = (x&1)<<11 | (y&15)<<7 | z      (12 bits)
//   label    = instance+1                     (6 bits, 1..50)

// ---------------------------------------------------------------------------
// 0) Zero the 512-word region-counter array.
// ---------------------------------------------------------------------------
__global__ __launch_bounds__(256) void zero_cnt_kernel(unsigned int* __restrict__ cnt) {
  cnt[threadIdx.x] = 0u;
  cnt[threadIdx.x + 256] = 0u;
}

// ---------------------------------------------------------------------------
// 1a) Binning with block-local counting sort (R7-proven structure, PPB=4096).
// ---------------------------------------------------------------------------
__global__ __launch_bounds__(256) void bin_kernel(
    const int* __restrict__ coords, const float* __restrict__ inst,
    unsigned int* __restrict__ cnt, unsigned int* __restrict__ bins, int N) {
  __shared__ unsigned lrec[PPB];     // 16 KB raw records
  __shared__ unsigned srec[PPB];     // 16 KB region-sorted records
  __shared__ unsigned hist[NREG];    // 2 KB: counts, then scatter cursor
  __shared__ unsigned lofs[NREG];    // 2 KB: block-local region starts
  __shared__ unsigned basec[NREG];   // 2 KB: global chunk base per region
  __shared__ unsigned part[256];     // 1 KB: scan workspace
  __shared__ unsigned total_sh;
  int tid = threadIdx.x;
  int start = blockIdx.x * PPB;
  for (int j = tid; j < NREG; j += 256) hist[j] = 0;
  __syncthreads();
  // phase 1: read points, build records in LDS, count per region
#pragma unroll
  for (int j = 0; j < PPB / 256; j++) {
    int i = start + j * 256 + tid;
    unsigned v = 0xFFFFFFFFu;
    if (i < N) {
      int x = coords[3 * i + 0];
      int y = coords[3 * i + 1];
      int z = coords[3 * i + 2];
      unsigned lab = (unsigned)inst[i] + 1u;                          // 1..50
      unsigned r = (((unsigned)x >> 1) << 3) | ((unsigned)y >> 4);    // 9 bits
      unsigned l = (((unsigned)x & 1) << 11) | (((unsigned)y & 15) << 7) | (unsigned)z;
      v = (r << 18) | (l << 6) | lab;
      atomicAdd(&hist[r], 1u);
    }
    lrec[j * 256 + tid] = v;
  }
  __syncthreads();
  // phase 2a: exclusive scan of hist[512] -> lofs (2 entries/thread)
  unsigned ha = hist[2 * tid], hb = hist[2 * tid + 1];
  part[tid] = ha + hb;
  __syncthreads();
  for (int o = 1; o < 256; o <<= 1) {
    unsigned v = part[tid];
    unsigned add = (tid >= o) ? part[tid - o] : 0u;
    __syncthreads();
    part[tid] = v + add;
    __syncthreads();
  }
  unsigned inc = part[tid];
  unsigned ex = inc - (ha + hb);
  lofs[2 * tid] = ex;
  lofs[2 * tid + 1] = ex + ha;
  if (tid == 255) total_sh = inc;
  __syncthreads();
  // phase 2b: reserve per-region chunks in global bins
  for (int j = tid; j < NREG; j += 256) {
    unsigned h = hist[j];
    basec[j] = h ? atomicAdd(&cnt[j], h) : 0u;
  }
  __syncthreads();
  for (int j = tid; j < NREG; j += 256) hist[j] = 0;   // reuse as cursor
  __syncthreads();
  // phase 3a: scatter records into region-sorted LDS buffer
#pragma unroll
  for (int j = 0; j < PPB / 256; j++) {
    unsigned v = lrec[j * 256 + tid];
    if (v != 0xFFFFFFFFu) {
      unsigned r = v >> 18;
      unsigned pos = lofs[r] + atomicAdd(&hist[r], 1u);
      srec[pos] = v;
    }
  }
  __syncthreads();
  // phase 3b: coalesced write-out
  unsigned total = total_sh;
  for (unsigned j = tid; j < total; j += 256) {
    unsigned v = srec[j];
    unsigned r = v >> 18;
    unsigned p = basec[r] + (j - lofs[r]);
    if (p < CAP) bins[r * CAP + p] = v & 0x3FFFFu;   // localvox<<6 | label
  }
}

// ---------------------------------------------------------------------------
// 1b+2) Build P for one region in LDS and pool its coarse cells (fused pool1).
//     Region r: x in {2X,2X+1} (X=r>>3), y in [yo*16,yo*16+16) (yo=r&7), z full.
//     A 2x2x2 pool block nests inside a region -> vs1/as1 from LDS.
// ---------------------------------------------------------------------------
__global__ __launch_bounds__(256) void build_pool_kernel(
    const unsigned int* __restrict__ cnt, const unsigned int* __restrict__ bins,
    unsigned int* __restrict__ P,
    double* __restrict__ vs1, double* __restrict__ as1) {
  __shared__ unsigned grid[RVOX];    // 16 KB
  int r = blockIdx.x;
  int tid = threadIdx.x;
  for (int j = tid; j < RVOX; j += 256) grid[j] = 0;
  __syncthreads();
  int n = min((int)cnt[r], CAP);
  for (int k = tid; k < n; k += 256) {
    unsigned v = bins[r * CAP + k];
    atomicAdd(&grid[v >> 6], (1u << 20) | (v & 63u));
  }
  __syncthreads();
  int X = r >> 3, yo = r & 7;        // x-pair index, y-16th index
  // write P: for each dx, a contiguous 8KB span (16y * 128z dwords)
  unsigned pbase = ((unsigned)(2 * X) << 14) | ((unsigned)yo << 11);
  for (int j = tid; j < RVOX; j += 256) {
    // j = (x&1)<<11 | (y&15)<<7 | z
    P[pbase + ((j >> 11) << 14) + (j & 0x7FF)] = grid[j];
  }
  // fused pool1: 512 coarse cells (1 X-plane, 8 coarse y, 64 coarse z)
  for (int c = tid; c < 512; c += 256) {
    int yl = c >> 6, Z = c & 63;
    double vs = 0.0, as = 0.0;
#pragma unroll
    for (int dx = 0; dx < 2; dx++)
#pragma unroll
      for (int dy = 0; dy < 2; dy++)
#pragma unroll
        for (int dz = 0; dz < 2; dz++) {
          int j = (dx << 11) | ((2 * yl + dy) << 7) | (2 * Z + dz);
          unsigned pk = grid[j];
          unsigned cc = pk >> 20;
          if (cc) {
            vs += (double)(pk & 0xFFFFFu) / (double)cc;
            as += 1.0;
          }
        }
    int q = (X << 12) | (((yo << 3) + yl) << 6) | Z;
    vs1[q] = vs;
    as1[q] = as;
  }
}

// ---------------------------------------------------------------------------
// 3) Pool scales 2..5 from scale-1 sums (sums are additive).
// ---------------------------------------------------------------------------
__global__ __launch_bounds__(256) void poolRest_kernel(
    const double* __restrict__ vs1, const double* __restrict__ as1,
    double* __restrict__ vs2, double* __restrict__ as2,
    double* __restrict__ vs3, double* __restrict__ as3,
    double* __restrict__ vs4, double* __restrict__ as4,
    double* __restrict__ vs5, double* __restrict__ as5) {
  int t = blockIdx.x * blockDim.x + threadIdx.x;

  if (t < NS2) {
    int q = t;
    int X = q >> 10, Y = (q >> 5) & 31, Z = q & 31;
    double vs = 0.0, as = 0.0;
#pragma unroll
    for (int dx = 0; dx < 2; dx++)
#pragma unroll
      for (int dy = 0; dy < 2; dy++)
#pragma unroll
        for (int dz = 0; dz < 2; dz++) {
          int p = ((((X << 1) + dx) << 12) + (((Y << 1) + dy) << 6) + ((Z << 1) + dz));
          vs += vs1[p];
          as += as1[p];
        }
    vs2[q] = vs;
    as2[q] = as;
    return;
  }
  t -= NS2;
  if (t < NS3) {
    int q = t;
    int X = q >> 8, Y = (q >> 4) & 15, Z = q & 15;
    double vs = 0.0, as = 0.0;
    for (int dx = 0; dx < 4; dx++)
      for (int dy = 0; dy < 4; dy++)
#pragma unroll
        for (int dz = 0; dz < 4; dz++) {
          int p = ((((X << 2) + dx) << 12) + (((Y << 2) + dy) << 6) + ((Z << 2) + dz));
          vs += vs1[p];
          as += as1[p];
        }
    vs3[q] = vs;
    as3[q] = as;
    return;
  }
  t -= NS3;
  if (t < NS4 * 64) {
    int w = t >> 6, lane = t & 63;
    int X = w >> 6, Y = (w >> 3) & 7, Z = w & 7;
    double vs = 0.0, as = 0.0;
#pragma unroll
    for (int j = 0; j < 8; j++) {
      int c = lane * 8 + j;
      int dx = c >> 6, dy = (c >> 3) & 7, dz = c & 7;
      int p = ((((X << 3) + dx) << 12) + (((Y << 3) + dy) << 6) + ((Z << 3) + dz));
      vs += vs1[p];
      as += as1[p];
    }
    for (int o = 32; o > 0; o >>= 1) {
      vs += __shfl_down(vs, o, 64);
      as += __shfl_down(as, o, 64);
    }
    if (lane == 0) { vs4[w] = vs; as4[w] = as; }
    return;
  }
  t -= NS4 * 64;
  if (t < NS5 * 64) {
    int w = t >> 6, lane = t & 63;
    int X = w >> 4, Y = (w >> 2) & 3, Z = w & 3;
    double vs = 0.0, as = 0.0;
    for (int j = 0; j < 64; j++) {
      int c = lane * 64 + j;
      int dx = c >> 8, dy = (c >> 4) & 15, dz = c & 15;
      int p = ((((X << 4) + dx) << 12) + (((Y << 4) + dy) << 6) + ((Z << 4) + dz));
      vs += vs1[p];
      as += as1[p];
    }
    for (int o = 32; o > 0; o >>= 1) {
      vs += __shfl_down(vs, o, 64);
      as += __shfl_down(as, o, 64);
    }
    if (lane == 0) { vs5[w] = vs; as5[w] = as; }
  }
}

// ---------------------------------------------------------------------------
// 4) Fused output kernel (R7-proven).
// ---------------------------------------------------------------------------
__global__ __launch_bounds__(256) void out_kernel(
    const unsigned int* __restrict__ P,
    const double* __restrict__ vs1, const double* __restrict__ as1,
    const double* __restrict__ vs2, const double* __restrict__ as2,
    const double* __restrict__ vs3, const double* __restrict__ as3,
    const double* __restrict__ vs4, const double* __restrict__ as4,
    const double* __restrict__ vs5, const double* __restrict__ as5,
    float* __restrict__ out) {
  int p = blockIdx.x * blockDim.x + threadIdx.x;
  if (p < GS3) {
    unsigned pk = P[p];
    int cc = (int)(pk >> 20);
    float4 r0 = {0.f, 0.f, 0.f, 0.f}, r1 = r0, r2 = r0;
    if (cc) {
      int sc = (int)(pk & 0xFFFFFu);
      int x = p >> 14, y = (p >> 7) & 127, z = p & 127;
      const int off[6] = {-(1 << 14), (1 << 14), -(1 << 7), (1 << 7), -1, 1};
      const bool inb[6] = {x > 0, x < 127, y > 0, y < 127, z > 0, z < 127};
      float f[6], m[6];
#pragma unroll
      for (int k = 0; k < 6; k++) {
        int sn = 0, cn = 0;
        if (inb[k]) {
          unsigned pn = P[p + off[k]];
          cn = (int)(pn >> 20);
          sn = (int)(pn & 0xFFFFFu);
        }
        if (cn) {
          long long d = (long long)sn * cc - (long long)sc * cn;
          if (d < 0) d = -d;
          f[k] = (100ll * d < (long long)cn * cc) ? 1.f : 0.f;
          m[k] = 1.f;
        } else {
          f[k] = 0.f;                          // vc >= 1 so |0-vc| >= 1
          m[k] = 0.f;
        }
      }
      r0 = {f[0], f[1], f[2], f[3]};
      r1 = {f[4], f[5], m[0], m[1]};
      r2 = {m[2], m[3], m[4], m[5]};
    }
    float4* o = (float4*)(out + 12ll * p);
    o[0] = r0; o[1] = r1; o[2] = r2;
    return;
  }
  int t = p - GS3;
  const double *vs, *as;
  int ls, q;
  long long obase;
  if (t < NS1) { q = t; vs = vs1; as = as1; ls = 6; obase = OB1; }
  else if (t < NS1 + NS2) { q = t - NS1; vs = vs2; as = as2; ls = 5; obase = OB2; }
  else if (t < NS1 + NS2 + NS3) { q = t - NS1 - NS2; vs = vs3; as = as3; ls = 4; obase = OB3; }
  else if (t < NS1 + NS2 + NS3 + NS4) { q = t - NS1 - NS2 - NS3; vs = vs4; as = as4; ls = 3; obase = OB4; }
  else if (t < NSALL) { q = t - NS1 - NS2 - NS3 - NS4; vs = vs5; as = as5; ls = 2; obase = OB5; }
  else return;

  int Ss = 1 << ls;
  int X = q >> (2 * ls), Y = (q >> ls) & (Ss - 1), Z = q & (Ss - 1);
  double ac = as[q];
  float4 r0 = {0.f, 0.f, 0.f, 0.f}, r1 = r0, r2 = r0;
  if (ac > 0.0) {
    double vc = vs[q] / ac;
    const int off[6] = {-(Ss * Ss), Ss * Ss, -Ss, Ss, -1, 1};
    const bool inb[6] = {X > 0, X < Ss - 1, Y > 0, Y < Ss - 1, Z > 0, Z < Ss - 1};
    float f[6], m[6];
#pragma unroll
    for (int k = 0; k < 6; k++) {
      double van = 0.0;
      if (inb[k]) {
        double an = as[q + off[k]];
        if (an > 0.0) van = vs[q + off[k]] / an;
      }
      f[k] = (fabs(van - vc) < 0.01) ? 1.f : 0.f;
      m[k] = (van > 0.0) ? 1.f : 0.f;
    }
    r0 = {f[0], f[1], f[2], f[3]};
    r1 = {f[4], f[5], m[0], m[1]};
    r2 = {m[2], m[3], m[4], m[5]};
  }
  float4* o = (float4*)(out + obase + 12ll * q);
  o[0] = r0; o[1] = r1; o[2] = r2;
}

// ---------------------------------------------------------------------------
extern "C" void kernel_launch(void* const* d_in, const int* in_sizes, int n_in,
                              void* d_out, int out_size, void* d_ws, size_t ws_size,
                              hipStream_t stream) {
  const int* coords = (const int*)d_in[0];
  const float* inst = (const float*)d_in[1];
  int N = in_sizes[1];            // 4,000,000 points
  float* out = (float*)d_out;

  // workspace layout
  char* base = (char*)d_ws;
  unsigned int* P = (unsigned int*)base;                 // 8 MB
  double* vs1 = (double*)(base + 8388608);
  double* as1 = vs1 + NS1;
  double* vs2 = as1 + NS1; double* as2 = vs2 + NS2;
  double* vs3 = as2 + NS2; double* as3 = vs3 + NS3;
  double* vs4 = as3 + NS3; double* as4 = vs4 + NS4;
  double* vs5 = as4 + NS4; double* as5 = vs5 + NS5;     // ends ~13.18 MB
  size_t cnt_off = 13182976;                             // 1KB-aligned
  unsigned int* cnt  = (unsigned int*)(base + cnt_off);
  unsigned int* bins = (unsigned int*)(base + cnt_off + 2048);
  size_t need = cnt_off + 2048 + (size_t)NREG * CAP * 4; // ~34.2 MB
  if (ws_size < need) return;  // never happens at this problem size

  int nchunks = (N + PPB - 1) / PPB;
  zero_cnt_kernel<<<1, 256, 0, stream>>>(cnt);
  bin_kernel<<<nchunks, 256, 0, stream>>>(coords, inst, cnt, bins, N);
  build_pool_kernel<<<NREG, 256, 0, stream>>>(cnt, bins, P, vs1, as1);
  poolRest_kernel<<<(NS2 + NS3 + NS4 * 64 + NS5 * 64 + 255) / 256, 256, 0, stream>>>(
      vs1, as1, vs2, as2, vs3, as3, vs4, as4, vs5, as5);
  out_kernel<<<(GS3 + NSALL + 255) / 256, 256, 0, stream>>>(
      P, vs1, as1, vs2, as2, vs3, as3, vs4, as4, vs5, as5, out);
}

// Round 13
// 99.896 us; speedup vs baseline: 1.0980x; 1.0980x over previous
//
#include <hip/hip_runtime.h>

#define GS3 2097152          // 128^3
#define NS1 262144           // 64^3
#define NS2 32768            // 32^3
#define NS3 4096             // 16^3
#define NS4 512              // 8^3
#define NS5 64               // 4^3
#define NSALL 299584         // NS1+NS2+NS3+NS4+NS5

// Output element offsets (float index) for each scale's block of [Ss^3, 12]
#define OB1 25165824
#define OB2 28311552
#define OB3 28704768
#define OB4 28753920
#define OB5 28760064

#define NREG 512             // regions: x-pair (x>>1, 6b) * y-16th (y>>4, 3b)
#define RVOX 4096            // voxels per region: 2(x) * 16(y) * 128(z) = 16KB LDS
#define CAP  10240           // bin capacity per region (mean 7813, +27 sigma)
#define PPB  8192            // points per binning block
#define RPT  (PPB / 256)     // records per thread (register-staged)

// Record: (region<<18) | (localvoxel<<6) | label
//   region   = (x>>1)<<3 | (y>>4)             (9 bits)
//   localvox = (x&1)<<11 | (y&15)<<7 | z      (12 bits)
//   label    = instance+1                     (6 bits, 1..50)

// ---------------------------------------------------------------------------
// 0) Zero the 512-word region-counter array.
// ---------------------------------------------------------------------------
__global__ __launch_bounds__(256) void zero_cnt_kernel(unsigned int* __restrict__ cnt) {
  cnt[threadIdx.x] = 0u;
  cnt[threadIdx.x + 256] = 0u;
}

// ---------------------------------------------------------------------------
// 1a) Binning with block-local counting sort. Raw records held in REGISTERS
//     (32/thread, statically indexed) -> only the sorted buffer lives in LDS
//     (39KB total -> 4 blocks/CU) while keeping PPB=8192 chunks.
// ---------------------------------------------------------------------------
__global__ __launch_bounds__(256) void bin_kernel(
    const int* __restrict__ coords, const float* __restrict__ inst,
    unsigned int* __restrict__ cnt, unsigned int* __restrict__ bins, int N) {
  __shared__ unsigned srec[PPB];     // 32 KB region-sorted records
  __shared__ unsigned hist[NREG];    // 2 KB: counts, then scatter cursor
  __shared__ unsigned lofs[NREG];    // 2 KB: block-local region starts
  __shared__ unsigned basec[NREG];   // 2 KB: global chunk base per region
  __shared__ unsigned part[256];     // 1 KB: scan workspace
  __shared__ unsigned total_sh;
  unsigned vrec[RPT];                // register-staged raw records
  int tid = threadIdx.x;
  int start = blockIdx.x * PPB;
  for (int j = tid; j < NREG; j += 256) hist[j] = 0;
  __syncthreads();
  // phase 1: read points, build records in registers, count per region
#pragma unroll
  for (int j = 0; j < RPT; j++) {
    int i = start + j * 256 + tid;
    unsigned v = 0xFFFFFFFFu;
    if (i < N) {
      int x = coords[3 * i + 0];
      int y = coords[3 * i + 1];
      int z = coords[3 * i + 2];
      unsigned lab = (unsigned)inst[i] + 1u;                          // 1..50
      unsigned r = (((unsigned)x >> 1) << 3) | ((unsigned)y >> 4);    // 9 bits
      unsigned l = (((unsigned)x & 1) << 11) | (((unsigned)y & 15) << 7) | (unsigned)z;
      v = (r << 18) | (l << 6) | lab;
      atomicAdd(&hist[r], 1u);
    }
    vrec[j] = v;
  }
  __syncthreads();
  // phase 2a: exclusive scan of hist[512] -> lofs (2 entries/thread)
  unsigned ha = hist[2 * tid], hb = hist[2 * tid + 1];
  part[tid] = ha + hb;
  __syncthreads();
  for (int o = 1; o < 256; o <<= 1) {
    unsigned v = part[tid];
    unsigned add = (tid >= o) ? part[tid - o] : 0u;
    __syncthreads();
    part[tid] = v + add;
    __syncthreads();
  }
  unsigned inc = part[tid];
  unsigned ex = inc - (ha + hb);
  lofs[2 * tid] = ex;
  lofs[2 * tid + 1] = ex + ha;
  if (tid == 255) total_sh = inc;
  __syncthreads();
  // phase 2b: reserve per-region chunks in global bins
  for (int j = tid; j < NREG; j += 256) {
    unsigned h = hist[j];
    basec[j] = h ? atomicAdd(&cnt[j], h) : 0u;
  }
  __syncthreads();
  for (int j = tid; j < NREG; j += 256) hist[j] = 0;   // reuse as cursor
  __syncthreads();
  // phase 3a: scatter records from registers into region-sorted LDS buffer
#pragma unroll
  for (int j = 0; j < RPT; j++) {
    unsigned v = vrec[j];
    if (v != 0xFFFFFFFFu) {
      unsigned r = v >> 18;
      unsigned pos = lofs[r] + atomicAdd(&hist[r], 1u);
      srec[pos] = v;
    }
  }
  __syncthreads();
  // phase 3b: coalesced write-out
  unsigned total = total_sh;
  for (unsigned j = tid; j < total; j += 256) {
    unsigned v = srec[j];
    unsigned r = v >> 18;
    unsigned p = basec[r] + (j - lofs[r]);
    if (p < CAP) bins[r * CAP + p] = v & 0x3FFFFu;   // localvox<<6 | label
  }
}

// ---------------------------------------------------------------------------
// 1b+2) Build P for one region in LDS and pool its coarse cells (fused pool1).
//     Region r: x in {2X,2X+1} (X=r>>3), y in [yo*16,yo*16+16) (yo=r&7), z full.
//     A 2x2x2 pool block nests inside a region -> vs1/as1 from LDS.
// ---------------------------------------------------------------------------
__global__ __launch_bounds__(256) void build_pool_kernel(
    const unsigned int* __restrict__ cnt, const unsigned int* __restrict__ bins,
    unsigned int* __restrict__ P,
    double* __restrict__ vs1, double* __restrict__ as1) {
  __shared__ unsigned grid[RVOX];    // 16 KB
  int r = blockIdx.x;
  int tid = threadIdx.x;
  for (int j = tid; j < RVOX; j += 256) grid[j] = 0;
  __syncthreads();
  int n = min((int)cnt[r], CAP);
  for (int k = tid; k < n; k += 256) {
    unsigned v = bins[r * CAP + k];
    atomicAdd(&grid[v >> 6], (1u << 20) | (v & 63u));
  }
  __syncthreads();
  int X = r >> 3, yo = r & 7;        // x-pair index, y-16th index
  // write P: for each dx, a contiguous 8KB span (16y * 128z dwords)
  unsigned pbase = ((unsigned)(2 * X) << 14) | ((unsigned)yo << 11);
  for (int j = tid; j < RVOX; j += 256) {
    // j = (x&1)<<11 | (y&15)<<7 | z
    P[pbase + ((j >> 11) << 14) + (j & 0x7FF)] = grid[j];
  }
  // fused pool1: 512 coarse cells (1 X-plane, 8 coarse y, 64 coarse z)
  for (int c = tid; c < 512; c += 256) {
    int yl = c >> 6, Z = c & 63;
    double vs = 0.0, as = 0.0;
#pragma unroll
    for (int dx = 0; dx < 2; dx++)
#pragma unroll
      for (int dy = 0; dy < 2; dy++)
#pragma unroll
        for (int dz = 0; dz < 2; dz++) {
          int j = (dx << 11) | ((2 * yl + dy) << 7) | (2 * Z + dz);
          unsigned pk = grid[j];
          unsigned cc = pk >> 20;
          if (cc) {
            vs += (double)(pk & 0xFFFFFu) / (double)cc;
            as += 1.0;
          }
        }
    int q = (X << 12) | (((yo << 3) + yl) << 6) | Z;
    vs1[q] = vs;
    as1[q] = as;
  }
}

// ---------------------------------------------------------------------------
// 3) Pool scales 2..5 from scale-1 sums (sums are additive).
// ---------------------------------------------------------------------------
__global__ __launch_bounds__(256) void poolRest_kernel(
    const double* __restrict__ vs1, const double* __restrict__ as1,
    double* __restrict__ vs2, double* __restrict__ as2,
    double* __restrict__ vs3, double* __restrict__ as3,
    double* __restrict__ vs4, double* __restrict__ as4,
    double* __restrict__ vs5, double* __restrict__ as5) {
  int t = blockIdx.x * blockDim.x + threadIdx.x;

  if (t < NS2) {
    int q = t;
    int X = q >> 10, Y = (q >> 5) & 31, Z = q & 31;
    double vs = 0.0, as = 0.0;
#pragma unroll
    for (int dx = 0; dx < 2; dx++)
#pragma unroll
      for (int dy = 0; dy < 2; dy++)
#pragma unroll
        for (int dz = 0; dz < 2; dz++) {
          int p = ((((X << 1) + dx) << 12) + (((Y << 1) + dy) << 6) + ((Z << 1) + dz));
          vs += vs1[p];
          as += as1[p];
        }
    vs2[q] = vs;
    as2[q] = as;
    return;
  }
  t -= NS2;
  if (t < NS3) {
    int q = t;
    int X = q >> 8, Y = (q >> 4) & 15, Z = q & 15;
    double vs = 0.0, as = 0.0;
    for (int dx = 0; dx < 4; dx++)
      for (int dy = 0; dy < 4; dy++)
#pragma unroll
        for (int dz = 0; dz < 4; dz++) {
          int p = ((((X << 2) + dx) << 12) + (((Y << 2) + dy) << 6) + ((Z << 2) + dz));
          vs += vs1[p];
          as += as1[p];
        }
    vs3[q] = vs;
    as3[q] = as;
    return;
  }
  t -= NS3;
  if (t < NS4 * 64) {
    int w = t >> 6, lane = t & 63;
    int X = w >> 6, Y = (w >> 3) & 7, Z = w & 7;
    double vs = 0.0, as = 0.0;
#pragma unroll
    for (int j = 0; j < 8; j++) {
      int c = lane * 8 + j;
      int dx = c >> 6, dy = (c >> 3) & 7, dz = c & 7;
      int p = ((((X << 3) + dx) << 12) + (((Y << 3) + dy) << 6) + ((Z << 3) + dz));
      vs += vs1[p];
      as += as1[p];
    }
    for (int o = 32; o > 0; o >>= 1) {
      vs += __shfl_down(vs, o, 64);
      as += __shfl_down(as, o, 64);
    }
    if (lane == 0) { vs4[w] = vs; as4[w] = as; }
    return;
  }
  t -= NS4 * 64;
  if (t < NS5 * 64) {
    int w = t >> 6, lane = t & 63;
    int X = w >> 4, Y = (w >> 2) & 3, Z = w & 3;
    double vs = 0.0, as = 0.0;
    for (int j = 0; j < 64; j++) {
      int c = lane * 64 + j;
      int dx = c >> 8, dy = (c >> 4) & 15, dz = c & 15;
      int p = ((((X << 4) + dx) << 12) + (((Y << 4) + dy) << 6) + ((Z << 4) + dz));
      vs += vs1[p];
      as += as1[p];
    }
    for (int o = 32; o > 0; o >>= 1) {
      vs += __shfl_down(vs, o, 64);
      as += __shfl_down(as, o, 64);
    }
    if (lane == 0) { vs5[w] = vs; as5[w] = as; }
  }
}

// ---------------------------------------------------------------------------
// 4) Fused output kernel (R7-proven).
// ---------------------------------------------------------------------------
__global__ __launch_bounds__(256) void out_kernel(
    const unsigned int* __restrict__ P,
    const double* __restrict__ vs1, const double* __restrict__ as1,
    const double* __restrict__ vs2, const double* __restrict__ as2,
    const double* __restrict__ vs3, const double* __restrict__ as3,
    const double* __restrict__ vs4, const double* __restrict__ as4,
    const double* __restrict__ vs5, const double* __restrict__ as5,
    float* __restrict__ out) {
  int p = blockIdx.x * blockDim.x + threadIdx.x;
  if (p < GS3) {
    unsigned pk = P[p];
    int cc = (int)(pk >> 20);
    float4 r0 = {0.f, 0.f, 0.f, 0.f}, r1 = r0, r2 = r0;
    if (cc) {
      int sc = (int)(pk & 0xFFFFFu);
      int x = p >> 14, y = (p >> 7) & 127, z = p & 127;
      const int off[6] = {-(1 << 14), (1 << 14), -(1 << 7), (1 << 7), -1, 1};
      const bool inb[6] = {x > 0, x < 127, y > 0, y < 127, z > 0, z < 127};
      float f[6], m[6];
#pragma unroll
      for (int k = 0; k < 6; k++) {
        int sn = 0, cn = 0;
        if (inb[k]) {
          unsigned pn = P[p + off[k]];
          cn = (int)(pn >> 20);
          sn = (int)(pn & 0xFFFFFu);
        }
        if (cn) {
          long long d = (long long)sn * cc - (long long)sc * cn;
          if (d < 0) d = -d;
          f[k] = (100ll * d < (long long)cn * cc) ? 1.f : 0.f;
          m[k] = 1.f;
        } else {
          f[k] = 0.f;                          // vc >= 1 so |0-vc| >= 1
          m[k] = 0.f;
        }
      }
      r0 = {f[0], f[1], f[2], f[3]};
      r1 = {f[4], f[5], m[0], m[1]};
      r2 = {m[2], m[3], m[4], m[5]};
    }
    float4* o = (float4*)(out + 12ll * p);
    o[0] = r0; o[1] = r1; o[2] = r2;
    return;
  }
  int t = p - GS3;
  const double *vs, *as;
  int ls, q;
  long long obase;
  if (t < NS1) { q = t; vs = vs1; as = as1; ls = 6; obase = OB1; }
  else if (t < NS1 + NS2) { q = t - NS1; vs = vs2; as = as2; ls = 5; obase = OB2; }
  else if (t < NS1 + NS2 + NS3) { q = t - NS1 - NS2; vs = vs3; as = as3; ls = 4; obase = OB3; }
  else if (t < NS1 + NS2 + NS3 + NS4) { q = t - NS1 - NS2 - NS3; vs = vs4; as = as4; ls = 3; obase = OB4; }
  else if (t < NSALL) { q = t - NS1 - NS2 - NS3 - NS4; vs = vs5; as = as5; ls = 2; obase = OB5; }
  else return;

  int Ss = 1 << ls;
  int X = q >> (2 * ls), Y = (q >> ls) & (Ss - 1), Z = q & (Ss - 1);
  double ac = as[q];
  float4 r0 = {0.f, 0.f, 0.f, 0.f}, r1 = r0, r2 = r0;
  if (ac > 0.0) {
    double vc = vs[q] / ac;
    const int off[6] = {-(Ss * Ss), Ss * Ss, -Ss, Ss, -1, 1};
    const bool inb[6] = {X > 0, X < Ss - 1, Y > 0, Y < Ss - 1, Z > 0, Z < Ss - 1};
    float f[6], m[6];
#pragma unroll
    for (int k = 0; k < 6; k++) {
      double van = 0.0;
      if (inb[k]) {
        double an = as[q + off[k]];
        if (an > 0.0) van = vs[q + off[k]] / an;
      }
      f[k] = (fabs(van - vc) < 0.01) ? 1.f : 0.f;
      m[k] = (van > 0.0) ? 1.f : 0.f;
    }
    r0 = {f[0], f[1], f[2], f[3]};
    r1 = {f[4], f[5], m[0], m[1]};
    r2 = {m[2], m[3], m[4], m[5]};
  }
  float4* o = (float4*)(out + obase + 12ll * q);
  o[0] = r0; o[1] = r1; o[2] = r2;
}

// ---------------------------------------------------------------------------
extern "C" void kernel_launch(void* const* d_in, const int* in_sizes, int n_in,
                              void* d_out, int out_size, void* d_ws, size_t ws_size,
                              hipStream_t stream) {
  const int* coords = (const int*)d_in[0];
  const float* inst = (const float*)d_in[1];
  int N = in_sizes[1];            // 4,000,000 points
  float* out = (float*)d_out;

  // workspace layout
  char* base = (char*)d_ws;
  unsigned int* P = (unsigned int*)base;                 // 8 MB
  double* vs1 = (double*)(base + 8388608);
  double* as1 = vs1 + NS1;
  double* vs2 = as1 + NS1; double* as2 = vs2 + NS2;
  double* vs3 = as2 + NS2; double* as3 = vs3 + NS3;
  double* vs4 = as3 + NS3; double* as4 = vs4 + NS4;
  double* vs5 = as4 + NS4; double* as5 = vs5 + NS5;     // ends ~13.18 MB
  size_t cnt_off = 13182976;                             // 1KB-aligned
  unsigned int* cnt  = (unsigned int*)(base + cnt_off);
  unsigned int* bins = (unsigned int*)(base + cnt_off + 2048);
  size_t need = cnt_off + 2048 + (size_t)NREG * CAP * 4; // ~34.2 MB
  if (ws_size < need) return;  // never happens at this problem size

  int nchunks = (N + PPB - 1) / PPB;
  zero_cnt_kernel<<<1, 256, 0, stream>>>(cnt);
  bin_kernel<<<nchunks, 256, 0, stream>>>(coords, inst, cnt, bins, N);
  build_pool_kernel<<<NREG, 256, 0, stream>>>(cnt, bins, P, vs1, as1);
  poolRest_kernel<<<(NS2 + NS3 + NS4 * 64 + NS5 * 64 + 255) / 256, 256, 0, stream>>>(
      vs1, as1, vs2, as2, vs3, as3, vs4, as4, vs5, as5);
  out_kernel<<<(GS3 + NSALL + 255) / 256, 256, 0, stream>>>(
      P, vs1, as1, vs2, as2, vs3, as3, vs4, as4, vs5, as5, out);
}

// Round 14
// 86.302 us; speedup vs baseline: 1.2709x; 1.1575x over previous
//
#include <hip/hip_runtime.h>

#define GS3 2097152          // 128^3
#define NS1 262144           // 64^3
#define NS2 32768            // 32^3
#define NS3 4096             // 16^3
#define NS4 512              // 8^3
#define NS5 64               // 4^3
#define NSALL 299584         // NS1+NS2+NS3+NS4+NS5

// Output element offsets (float index) for each scale's block of [Ss^3, 12]
#define OB1 25165824
#define OB2 28311552
#define OB3 28704768
#define OB4 28753920
#define OB5 28760064

#define NREG 512             // regions: x-pair (x>>1, 6b) * y-16th (y>>4, 3b)
#define RVOX 4096            // voxels per region: 2(x) * 16(y) * 128(z) = 16KB LDS
#define PPB  8192            // points per binning block
#define RPT  (PPB / 256)     // records per thread (register-staged)
#define CAPB 64              // per-(block,region) slot capacity (mean 16, P(>64)~1e-17)

// Record: (region<<18) | (localvoxel<<6) | label
//   region   = (x>>1)<<3 | (y>>4)             (9 bits)
//   localvox = (x&1)<<11 | (y&15)<<7 | z      (12 bits)
//   label    = instance+1                     (6 bits, 1..50)

// ---------------------------------------------------------------------------
// 1a) Binning with block-local counting sort. Raw records in registers;
//     sorted runs written to FIXED per-(block,region) 256B slots -> no global
//     atomics anywhere, no counter zeroing, fully deterministic.
// ---------------------------------------------------------------------------
__global__ __launch_bounds__(256) void bin_kernel(
    const int* __restrict__ coords, const float* __restrict__ inst,
    unsigned int* __restrict__ counts, unsigned int* __restrict__ bins, int N) {
  __shared__ unsigned srec[PPB];     // 32 KB region-sorted records
  __shared__ unsigned hist[NREG];    // 2 KB: counts, then scatter cursor
  __shared__ unsigned lofs[NREG];    // 2 KB: block-local region starts
  __shared__ unsigned part[256];     // 1 KB: scan workspace
  __shared__ unsigned total_sh;
  unsigned vrec[RPT];                // register-staged raw records
  int tid = threadIdx.x;
  int bid = blockIdx.x;
  int start = bid * PPB;
  for (int j = tid; j < NREG; j += 256) hist[j] = 0;
  __syncthreads();
  // phase 1: read points, build records in registers, count per region
#pragma unroll
  for (int j = 0; j < RPT; j++) {
    int i = start + j * 256 + tid;
    unsigned v = 0xFFFFFFFFu;
    if (i < N) {
      int x = coords[3 * i + 0];
      int y = coords[3 * i + 1];
      int z = coords[3 * i + 2];
      unsigned lab = (unsigned)inst[i] + 1u;                          // 1..50
      unsigned r = (((unsigned)x >> 1) << 3) | ((unsigned)y >> 4);    // 9 bits
      unsigned l = (((unsigned)x & 1) << 11) | (((unsigned)y & 15) << 7) | (unsigned)z;
      v = (r << 18) | (l << 6) | lab;
      atomicAdd(&hist[r], 1u);
    }
    vrec[j] = v;
  }
  __syncthreads();
  // phase 2a: exclusive scan of hist[512] -> lofs (2 entries/thread);
  //           also store per-region counts (clamped) to global, non-atomic
  unsigned ha = hist[2 * tid], hb = hist[2 * tid + 1];
  counts[(size_t)bid * NREG + 2 * tid]     = ha < CAPB ? ha : CAPB;
  counts[(size_t)bid * NREG + 2 * tid + 1] = hb < CAPB ? hb : CAPB;
  part[tid] = ha + hb;
  __syncthreads();
  for (int o = 1; o < 256; o <<= 1) {
    unsigned v = part[tid];
    unsigned add = (tid >= o) ? part[tid - o] : 0u;
    __syncthreads();
    part[tid] = v + add;
    __syncthreads();
  }
  unsigned inc = part[tid];
  unsigned ex = inc - (ha + hb);
  lofs[2 * tid] = ex;
  lofs[2 * tid + 1] = ex + ha;
  if (tid == 255) total_sh = inc;
  __syncthreads();
  for (int j = tid; j < NREG; j += 256) hist[j] = 0;   // reuse as cursor
  __syncthreads();
  // phase 3a: scatter records from registers into region-sorted LDS buffer
#pragma unroll
  for (int j = 0; j < RPT; j++) {
    unsigned v = vrec[j];
    if (v != 0xFFFFFFFFu) {
      unsigned r = v >> 18;
      unsigned pos = lofs[r] + atomicAdd(&hist[r], 1u);
      srec[pos] = v;
    }
  }
  __syncthreads();
  // phase 3b: write sorted runs to fixed 256B-aligned slots (coalesced)
  unsigned total = total_sh;
  size_t bbase = (size_t)bid * NREG * CAPB;
  for (unsigned j = tid; j < total; j += 256) {
    unsigned v = srec[j];
    unsigned r = v >> 18;
    unsigned p = j - lofs[r];                 // position within region run
    if (p < CAPB) bins[bbase + r * CAPB + p] = v & 0x3FFFFu;
  }
}

// ---------------------------------------------------------------------------
// 1b+2) Build P for one region in LDS (gathering the per-block slots) and
//     pool its coarse cells (fused pool1).
//     Region r: x in {2X,2X+1} (X=r>>3), y in [yo*16,yo*16+16) (yo=r&7).
// ---------------------------------------------------------------------------
__global__ __launch_bounds__(256) void build_pool_kernel(
    const unsigned int* __restrict__ counts, const unsigned int* __restrict__ bins,
    unsigned int* __restrict__ P,
    double* __restrict__ vs1, double* __restrict__ as1, int nchunks) {
  __shared__ unsigned grid[RVOX];    // 16 KB
  int r = blockIdx.x;
  int tid = threadIdx.x;
  for (int j = tid; j < RVOX; j += 256) grid[j] = 0;
  __syncthreads();
  for (int b = tid; b < nchunks; b += 256) {
    int cb = (int)counts[(size_t)b * NREG + r];
    const unsigned* src = bins + ((size_t)b * NREG + r) * CAPB;
    for (int k = 0; k < cb; k++) {
      unsigned v = src[k];
      atomicAdd(&grid[v >> 6], (1u << 20) | (v & 63u));
    }
  }
  __syncthreads();
  int X = r >> 3, yo = r & 7;        // x-pair index, y-16th index
  // write P: for each dx, a contiguous 8KB span (16y * 128z dwords)
  unsigned pbase = ((unsigned)(2 * X) << 14) | ((unsigned)yo << 11);
  for (int j = tid; j < RVOX; j += 256) {
    // j = (x&1)<<11 | (y&15)<<7 | z
    P[pbase + ((j >> 11) << 14) + (j & 0x7FF)] = grid[j];
  }
  // fused pool1: 512 coarse cells (1 X-plane, 8 coarse y, 64 coarse z)
  for (int c = tid; c < 512; c += 256) {
    int yl = c >> 6, Z = c & 63;
    double vs = 0.0, as = 0.0;
#pragma unroll
    for (int dx = 0; dx < 2; dx++)
#pragma unroll
      for (int dy = 0; dy < 2; dy++)
#pragma unroll
        for (int dz = 0; dz < 2; dz++) {
          int j = (dx << 11) | ((2 * yl + dy) << 7) | (2 * Z + dz);
          unsigned pk = grid[j];
          unsigned cc = pk >> 20;
          if (cc) {
            vs += (double)(pk & 0xFFFFFu) / (double)cc;
            as += 1.0;
          }
        }
    int q = (X << 12) | (((yo << 3) + yl) << 6) | Z;
    vs1[q] = vs;
    as1[q] = as;
  }
}

// ---------------------------------------------------------------------------
// 3) Pool scales 2..5 from scale-1 sums (sums are additive).
// ---------------------------------------------------------------------------
__global__ __launch_bounds__(256) void poolRest_kernel(
    const double* __restrict__ vs1, const double* __restrict__ as1,
    double* __restrict__ vs2, double* __restrict__ as2,
    double* __restrict__ vs3, double* __restrict__ as3,
    double* __restrict__ vs4, double* __restrict__ as4,
    double* __restrict__ vs5, double* __restrict__ as5) {
  int t = blockIdx.x * blockDim.x + threadIdx.x;

  if (t < NS2) {
    int q = t;
    int X = q >> 10, Y = (q >> 5) & 31, Z = q & 31;
    double vs = 0.0, as = 0.0;
#pragma unroll
    for (int dx = 0; dx < 2; dx++)
#pragma unroll
      for (int dy = 0; dy < 2; dy++)
#pragma unroll
        for (int dz = 0; dz < 2; dz++) {
          int p = ((((X << 1) + dx) << 12) + (((Y << 1) + dy) << 6) + ((Z << 1) + dz));
          vs += vs1[p];
          as += as1[p];
        }
    vs2[q] = vs;
    as2[q] = as;
    return;
  }
  t -= NS2;
  if (t < NS3) {
    int q = t;
    int X = q >> 8, Y = (q >> 4) & 15, Z = q & 15;
    double vs = 0.0, as = 0.0;
    for (int dx = 0; dx < 4; dx++)
      for (int dy = 0; dy < 4; dy++)
#pragma unroll
        for (int dz = 0; dz < 4; dz++) {
          int p = ((((X << 2) + dx) << 12) + (((Y << 2) + dy) << 6) + ((Z << 2) + dz));
          vs += vs1[p];
          as += as1[p];
        }
    vs3[q] = vs;
    as3[q] = as;
    return;
  }
  t -= NS3;
  if (t < NS4 * 64) {
    int w = t >> 6, lane = t & 63;
    int X = w >> 6, Y = (w >> 3) & 7, Z = w & 7;
    double vs = 0.0, as = 0.0;
#pragma unroll
    for (int j = 0; j < 8; j++) {
      int c = lane * 8 + j;
      int dx = c >> 6, dy = (c >> 3) & 7, dz = c & 7;
      int p = ((((X << 3) + dx) << 12) + (((Y << 3) + dy) << 6) + ((Z << 3) + dz));
      vs += vs1[p];
      as += as1[p];
    }
    for (int o = 32; o > 0; o >>= 1) {
      vs += __shfl_down(vs, o, 64);
      as += __shfl_down(as, o, 64);
    }
    if (lane == 0) { vs4[w] = vs; as4[w] = as; }
    return;
  }
  t -= NS4 * 64;
  if (t < NS5 * 64) {
    int w = t >> 6, lane = t & 63;
    int X = w >> 4, Y = (w >> 2) & 3, Z = w & 3;
    double vs = 0.0, as = 0.0;
    for (int j = 0; j < 64; j++) {
      int c = lane * 64 + j;
      int dx = c >> 8, dy = (c >> 4) & 15, dz = c & 15;
      int p = ((((X << 4) + dx) << 12) + (((Y << 4) + dy) << 6) + ((Z << 4) + dz));
      vs += vs1[p];
      as += as1[p];
    }
    for (int o = 32; o > 0; o >>= 1) {
      vs += __shfl_down(vs, o, 64);
      as += __shfl_down(as, o, 64);
    }
    if (lane == 0) { vs5[w] = vs; as5[w] = as; }
  }
}

// ---------------------------------------------------------------------------
// 4) Fused output kernel (R7-proven).
// ---------------------------------------------------------------------------
__global__ __launch_bounds__(256) void out_kernel(
    const unsigned int* __restrict__ P,
    const double* __restrict__ vs1, const double* __restrict__ as1,
    const double* __restrict__ vs2, const double* __restrict__ as2,
    const double* __restrict__ vs3, const double* __restrict__ as3,
    const double* __restrict__ vs4, const double* __restrict__ as4,
    const double* __restrict__ vs5, const double* __restrict__ as5,
    float* __restrict__ out) {
  int p = blockIdx.x * blockDim.x + threadIdx.x;
  if (p < GS3) {
    unsigned pk = P[p];
    int cc = (int)(pk >> 20);
    float4 r0 = {0.f, 0.f, 0.f, 0.f}, r1 = r0, r2 = r0;
    if (cc) {
      int sc = (int)(pk & 0xFFFFFu);
      int x = p >> 14, y = (p >> 7) & 127, z = p & 127;
      const int off[6] = {-(1 << 14), (1 << 14), -(1 << 7), (1 << 7), -1, 1};
      const bool inb[6] = {x > 0, x < 127, y > 0, y < 127, z > 0, z < 127};
      float f[6], m[6];
#pragma unroll
      for (int k = 0; k < 6; k++) {
        int sn = 0, cn = 0;
        if (inb[k]) {
          unsigned pn = P[p + off[k]];
          cn = (int)(pn >> 20);
          sn = (int)(pn & 0xFFFFFu);
        }
        if (cn) {
          long long d = (long long)sn * cc - (long long)sc * cn;
          if (d < 0) d = -d;
          f[k] = (100ll * d < (long long)cn * cc) ? 1.f : 0.f;
          m[k] = 1.f;
        } else {
          f[k] = 0.f;                          // vc >= 1 so |0-vc| >= 1
          m[k] = 0.f;
        }
      }
      r0 = {f[0], f[1], f[2], f[3]};
      r1 = {f[4], f[5], m[0], m[1]};
      r2 = {m[2], m[3], m[4], m[5]};
    }
    float4* o = (float4*)(out + 12ll * p);
    o[0] = r0; o[1] = r1; o[2] = r2;
    return;
  }
  int t = p - GS3;
  const double *vs, *as;
  int ls, q;
  long long obase;
  if (t < NS1) { q = t; vs = vs1; as = as1; ls = 6; obase = OB1; }
  else if (t < NS1 + NS2) { q = t - NS1; vs = vs2; as = as2; ls = 5; obase = OB2; }
  else if (t < NS1 + NS2 + NS3) { q = t - NS1 - NS2; vs = vs3; as = as3; ls = 4; obase = OB3; }
  else if (t < NS1 + NS2 + NS3 + NS4) { q = t - NS1 - NS2 - NS3; vs = vs4; as = as4; ls = 3; obase = OB4; }
  else if (t < NSALL) { q = t - NS1 - NS2 - NS3 - NS4; vs = vs5; as = as5; ls = 2; obase = OB5; }
  else return;

  int Ss = 1 << ls;
  int X = q >> (2 * ls), Y = (q >> ls) & (Ss - 1), Z = q & (Ss - 1);
  double ac = as[q];
  float4 r0 = {0.f, 0.f, 0.f, 0.f}, r1 = r0, r2 = r0;
  if (ac > 0.0) {
    double vc = vs[q] / ac;
    const int off[6] = {-(Ss * Ss), Ss * Ss, -Ss, Ss, -1, 1};
    const bool inb[6] = {X > 0, X < Ss - 1, Y > 0, Y < Ss - 1, Z > 0, Z < Ss - 1};
    float f[6], m[6];
#pragma unroll
    for (int k = 0; k < 6; k++) {
      double van = 0.0;
      if (inb[k]) {
        double an = as[q + off[k]];
        if (an > 0.0) van = vs[q + off[k]] / an;
      }
      f[k] = (fabs(van - vc) < 0.01) ? 1.f : 0.f;
      m[k] = (van > 0.0) ? 1.f : 0.f;
    }
    r0 = {f[0], f[1], f[2], f[3]};
    r1 = {f[4], f[5], m[0], m[1]};
    r2 = {m[2], m[3], m[4], m[5]};
  }
  float4* o = (float4*)(out + obase + 12ll * q);
  o[0] = r0; o[1] = r1; o[2] = r2;
}

// ---------------------------------------------------------------------------
extern "C" void kernel_launch(void* const* d_in, const int* in_sizes, int n_in,
                              void* d_out, int out_size, void* d_ws, size_t ws_size,
                              hipStream_t stream) {
  const int* coords = (const int*)d_in[0];
  const float* inst = (const float*)d_in[1];
  int N = in_sizes[1];            // 4,000,000 points
  float* out = (float*)d_out;
  int nchunks = (N + PPB - 1) / PPB;                     // 489

  // workspace layout
  char* base = (char*)d_ws;
  unsigned int* P = (unsigned int*)base;                 // 8 MB
  double* vs1 = (double*)(base + 8388608);
  double* as1 = vs1 + NS1;
  double* vs2 = as1 + NS1; double* as2 = vs2 + NS2;
  double* vs3 = as2 + NS2; double* as3 = vs3 + NS3;
  double* vs4 = as3 + NS3; double* as4 = vs4 + NS4;
  double* vs5 = as4 + NS4; double* as5 = vs5 + NS5;     // ends ~13.18 MB
  size_t counts_off = 13182976;                          // 1KB-aligned
  unsigned int* counts = (unsigned int*)(base + counts_off);
  size_t bins_off = counts_off + ((size_t)nchunks * NREG * 4 + 1023) / 1024 * 1024;
  unsigned int* bins = (unsigned int*)(base + bins_off);
  size_t need = bins_off + (size_t)nchunks * NREG * CAPB * 4;  // ~78.4 MB
  if (ws_size < need) return;  // never happens at this problem size

  bin_kernel<<<nchunks, 256, 0, stream>>>(coords, inst, counts, bins, N);
  build_pool_kernel<<<NREG, 256, 0, stream>>>(counts, bins, P, vs1, as1, nchunks);
  poolRest_kernel<<<(NS2 + NS3 + NS4 * 64 + NS5 * 64 + 255) / 256, 256, 0, stream>>>(
      vs1, as1, vs2, as2, vs3, as3, vs4, as4, vs5, as5);
  out_kernel<<<(GS3 + NSALL + 255) / 256, 256, 0, stream>>>(
      P, vs1, as1, vs2, as2, vs3, as3, vs4, as4, vs5, as5, out);
}